// Round 7
// baseline (218.067 us; speedup 1.0000x reference)
//
#include <hip/hip_runtime.h>
#include <hip/hip_fp16.h>

#define BB 4
#define SS 4096
#define DD 64
#define NSPLIT 4                 // K-split factor: 1024 blocks (4/CU)
#define KT_PER (SS / 64 / NSPLIT)

typedef _Float16 half8 __attribute__((ext_vector_type(8)));
typedef _Float16 half4 __attribute__((ext_vector_type(4)));
typedef __fp16 fp16x2 __attribute__((ext_vector_type(2)));   // cvt_pkrtz return type
typedef float floatx4 __attribute__((ext_vector_type(4)));

// Kernel A: Q = X*R, K = X*E in fp32, stored as hi/lo fp16 pairs (Markidis split).
// 64 rows/block, thread = 4 rows x 4 cols: per-d LDS = 4 broadcast b32 + 2 b128
// for 32 outputs (vs 1 b32 + 2 b128 for 8 in R3's version) -> ~2.5x less LDS traffic.
__global__ __launch_bounds__(256) void proj_kernel(
    const float* __restrict__ X, const float* __restrict__ R, const float* __restrict__ E,
    _Float16* __restrict__ Qhi, _Float16* __restrict__ Qlo,
    _Float16* __restrict__ Khi, _Float16* __restrict__ Klo,
    _Float16* __restrict__ Vt)
{
    __shared__ float Rs[64][64];
    __shared__ float Es[64][64];
    __shared__ float Xs[64][68];     // pad 68 breaks stride-64 conflicts on transposed reads
    int t = threadIdx.x;
    long rowbase = (long)blockIdx.x * 64;

    const float4* Xg = (const float4*)(X + rowbase * 64);
    for (int j = 0; j < 4; ++j) {
        int idx = j * 256 + t;       // 1024 float4 per 64x64 matrix
        int r = idx >> 4;
        int c = (idx & 15) * 4;
        *(float4*)&Rs[r][c] = ((const float4*)R)[idx];
        *(float4*)&Es[r][c] = ((const float4*)E)[idx];
        *(float4*)&Xs[r][c] = Xg[idx];
    }
    __syncthreads();

    int rg = t >> 4;                 // row group: rows rg*4 .. rg*4+3
    int c0 = (t & 15) * 4;           // 4 cols
    float q[4][4], k[4][4];
    for (int i = 0; i < 4; ++i)
        for (int j = 0; j < 4; ++j) { q[i][j] = 0.f; k[i][j] = 0.f; }
#pragma unroll 4
    for (int d = 0; d < 64; ++d) {
        float4 rv = *(const float4*)&Rs[d][c0];   // ds_read_b128
        float4 ev = *(const float4*)&Es[d][c0];
        for (int i = 0; i < 4; ++i) {
            float x = Xs[rg * 4 + i][d];          // broadcast within 16-lane group
            q[i][0] = fmaf(x, rv.x, q[i][0]); q[i][1] = fmaf(x, rv.y, q[i][1]);
            q[i][2] = fmaf(x, rv.z, q[i][2]); q[i][3] = fmaf(x, rv.w, q[i][3]);
            k[i][0] = fmaf(x, ev.x, k[i][0]); k[i][1] = fmaf(x, ev.y, k[i][1]);
            k[i][2] = fmaf(x, ev.z, k[i][2]); k[i][3] = fmaf(x, ev.w, k[i][3]);
        }
    }
    for (int i = 0; i < 4; ++i) {
        long gq = (rowbase + rg * 4 + i) * 64 + c0;
        half4 qh, ql, kh, kl;
        for (int j = 0; j < 4; ++j) {
            _Float16 h = (_Float16)q[i][j];
            qh[j] = h; ql[j] = (_Float16)(q[i][j] - (float)h);
            h = (_Float16)k[i][j];
            kh[j] = h; kl[j] = (_Float16)(k[i][j] - (float)h);
        }
        *(half4*)(Qhi + gq) = qh; *(half4*)(Qlo + gq) = ql;
        *(half4*)(Khi + gq) = kh; *(half4*)(Klo + gq) = kl;
    }

    // V^T: Vt[b][d][s] = X[b][s][d] fp16; thread = row d, 16 key-cols
    int d = t >> 2;                  // 0..63
    int si = (t & 3) * 16;           // 0..48
    int b = (int)(rowbase >> 12);
    int sbase = (int)(rowbase & 4095);
    half8 v0, v1;
    for (int j = 0; j < 8; ++j) {
        v0[j] = (_Float16)Xs[si + j][d];
        v1[j] = (_Float16)Xs[si + 8 + j][d];
    }
    _Float16* vp = Vt + ((long)(b * 64 + d)) * SS + sbase + si;
    *(half8*)vp = v0;
    *(half8*)(vp + 8) = v1;
}

#define L2E 1.44269504088896340736f
#define PD 72   // LDS row pad: 144B stride -> 2-way (free) instead of 16-way on b128 frag reads

// Kernel B: flash attention partial over 1/NSPLIT of the keys.
// 128 threads = 2 waves x 32 queries (64 q/block). Each wave computes S^T for
// TWO 16-query column tiles per K-fragment read -> halves per-CU LDS traffic
// (the R6 bottleneck: ~80% LDS-pipe busy).
__global__ __launch_bounds__(128, 2) void attn_partial(
    const _Float16* __restrict__ Qhi, const _Float16* __restrict__ Qlo,
    const _Float16* __restrict__ Khi, const _Float16* __restrict__ Klo,
    const _Float16* __restrict__ Vt,
    float* __restrict__ Op, float* __restrict__ Mp, float* __restrict__ Lp)
{
    __shared__ _Float16 Ksh[64][PD];
    __shared__ _Float16 Ksl[64][PD];
    __shared__ _Float16 Vs[64][PD];
    __shared__ _Float16 Ps[2][32][PD];   // [wave][query][key]

    int t = threadIdx.x;
    int wave = t >> 6;
    int lane = t & 63;
    int l15 = lane & 15;
    int quad = lane >> 4;
    int split = blockIdx.y;
    int b = blockIdx.z;
    int q0 = blockIdx.x * 64 + wave * 32;

    // Q fragments (B-operand for S^T), two 16-query halves per wave
    half8 qah[2][2], qal[2][2];
    for (int qh = 0; qh < 2; ++qh) {
        long qrow = ((long)b * SS + q0 + qh * 16 + l15) * DD;
        qah[qh][0] = *(const half8*)(Qhi + qrow + quad * 8);
        qah[qh][1] = *(const half8*)(Qhi + qrow + 32 + quad * 8);
        qal[qh][0] = *(const half8*)(Qlo + qrow + quad * 8);
        qal[qh][1] = *(const half8*)(Qlo + qrow + 32 + quad * 8);
    }

    floatx4 o[2][4];
    for (int qh = 0; qh < 2; ++qh)
        for (int i = 0; i < 4; ++i) o[qh][i] = (floatx4){0.f, 0.f, 0.f, 0.f};
    float m_q[2] = {-1e30f, -1e30f};
    float l_q[2] = {0.f, 0.f};

    const float scale = 0.125f * L2E;

    // staging: each of 128 threads stages 4x16B chunks per array.
    // chunk c = j*128 + t: row = c>>3, elem = (c&7)*8 (row-major 64x64 fp16 tile)
    int erow = t >> 3;               // base row for j=0 (rows 0..15)
    int eel = (t & 7) * 8;
    long ktilebase = ((long)b * SS) * DD;        // + kt*64*DD + c*8
    int kt = split * KT_PER;

    uint4 rh[4], rl[4], rv[4];
    {
        const uint4* khsrc = (const uint4*)(Khi + ktilebase + (long)kt * 64 * DD) + t;
        const uint4* klsrc = (const uint4*)(Klo + ktilebase + (long)kt * 64 * DD) + t;
        for (int j = 0; j < 4; ++j) {
            rh[j] = khsrc[j * 128];
            rl[j] = klsrc[j * 128];
            int d = j * 16 + erow;
            rv[j] = *(const uint4*)(Vt + ((long)(b * 64 + d)) * SS + kt * 64 + eel);
        }
    }

    for (int i = 0; i < KT_PER; ++i) {
        if (i > 0) __syncthreads();          // previous tile's compute done
        for (int j = 0; j < 4; ++j) {
            int rr = j * 16 + erow;
            *(uint4*)&Ksh[rr][eel] = rh[j];
            *(uint4*)&Ksl[rr][eel] = rl[j];
            *(uint4*)&Vs[rr][eel] = rv[j];
        }
        __syncthreads();                     // LDS tile ready

        // issue next tile's global loads (overlap with compute below)
        int ktn = (i + 1 < KT_PER) ? (kt + 1) : kt;   // clamp: harmless reload on last iter
        {
            const uint4* khsrc = (const uint4*)(Khi + ktilebase + (long)ktn * 64 * DD) + t;
            const uint4* klsrc = (const uint4*)(Klo + ktilebase + (long)ktn * 64 * DD) + t;
            for (int j = 0; j < 4; ++j) {
                rh[j] = khsrc[j * 128];
                rl[j] = klsrc[j * 128];
                int d = j * 16 + erow;
                rv[j] = *(const uint4*)(Vt + ((long)(b * 64 + d)) * SS + ktn * 64 + eel);
            }
        }
        kt = ktn;

        // S^T = K Q^T (fp32-accurate via hi/lo): C[key=quad*4+r][query=l15]
        // One K-fragment read feeds BOTH query halves (the LDS-traffic win).
        floatx4 s[2][4];
        for (int ct = 0; ct < 4; ++ct) {
            half8 ka0h = *(const half8*)&Ksh[ct * 16 + l15][quad * 8];
            half8 ka1h = *(const half8*)&Ksh[ct * 16 + l15][32 + quad * 8];
            half8 ka0l = *(const half8*)&Ksl[ct * 16 + l15][quad * 8];
            half8 ka1l = *(const half8*)&Ksl[ct * 16 + l15][32 + quad * 8];
            for (int qh = 0; qh < 2; ++qh) {
                floatx4 acc = {0.f, 0.f, 0.f, 0.f};
                acc = __builtin_amdgcn_mfma_f32_16x16x32_f16(ka0h, qah[qh][0], acc, 0, 0, 0);
                acc = __builtin_amdgcn_mfma_f32_16x16x32_f16(ka1h, qah[qh][1], acc, 0, 0, 0);
                acc = __builtin_amdgcn_mfma_f32_16x16x32_f16(ka0h, qal[qh][0], acc, 0, 0, 0);
                acc = __builtin_amdgcn_mfma_f32_16x16x32_f16(ka1h, qal[qh][1], acc, 0, 0, 0);
                acc = __builtin_amdgcn_mfma_f32_16x16x32_f16(ka0l, qah[qh][0], acc, 0, 0, 0);
                acc = __builtin_amdgcn_mfma_f32_16x16x32_f16(ka1l, qah[qh][1], acc, 0, 0, 0);
                s[qh][ct] = acc;
            }
        }

        // per-lane softmax for each query half (query = q0 + qh*16 + l15)
        float alpha[2];
        for (int qh = 0; qh < 2; ++qh) {
            float mt = s[qh][0][0];
            for (int ct = 0; ct < 4; ++ct)
                for (int r = 0; r < 4; ++r)
                    mt = fmaxf(mt, s[qh][ct][r]);
            mt = fmaxf(mt, __shfl_xor(mt, 16));
            mt = fmaxf(mt, __shfl_xor(mt, 32));
            mt *= scale;
            float mn = fmaxf(m_q[qh], mt);
            alpha[qh] = exp2f(m_q[qh] - mn);     // 0 on first tile
            m_q[qh] = mn;

            float rs = 0.f;
            for (int ct = 0; ct < 4; ++ct) {
                float p0 = exp2f(s[qh][ct][0] * scale - mn);
                float p1 = exp2f(s[qh][ct][1] * scale - mn);
                float p2 = exp2f(s[qh][ct][2] * scale - mn);
                float p3 = exp2f(s[qh][ct][3] * scale - mn);
                rs += (p0 + p1) + (p2 + p3);
                union { fp16x2 h2[2]; half4 h4; } u;
                u.h2[0] = __builtin_amdgcn_cvt_pkrtz(p0, p1);
                u.h2[1] = __builtin_amdgcn_cvt_pkrtz(p2, p3);
                *(half4*)&Ps[wave][qh * 16 + l15][ct * 16 + quad * 4] = u.h4;
            }
            rs += __shfl_xor(rs, 16);            // cross-quad SUM (full 64-key row)
            rs += __shfl_xor(rs, 32);
            l_q[qh] = l_q[qh] * alpha[qh] + rs;

            // rescale O (C-layout rows = query quad*4+r): gather that query's alpha
            for (int r = 0; r < 4; ++r) {
                float a = __shfl(alpha[qh], quad * 4 + r);
                o[qh][0][r] *= a; o[qh][1][r] *= a;
                o[qh][2][r] *= a; o[qh][3][r] *= a;
            }
        }

        // O += P V : A = Ps (m=query, k=key), B = Vs rows (n=d, k=key)
        for (int h = 0; h < 2; ++h) {
            half8 pa0 = *(const half8*)&Ps[wave][l15][h * 32 + quad * 8];
            half8 pa1 = *(const half8*)&Ps[wave][16 + l15][h * 32 + quad * 8];
            for (int dt = 0; dt < 4; ++dt) {
                half8 vb = *(const half8*)&Vs[dt * 16 + l15][h * 32 + quad * 8];
                o[0][dt] = __builtin_amdgcn_mfma_f32_16x16x32_f16(pa0, vb, o[0][dt], 0, 0, 0);
                o[1][dt] = __builtin_amdgcn_mfma_f32_16x16x32_f16(pa1, vb, o[1][dt], 0, 0, 0);
            }
        }
    }

    // store unnormalized partial O (rows = query qh*16+quad*4+r) and per-query (m, l)
    long pbase = ((long)b * NSPLIT + split) * SS;
    for (int qh = 0; qh < 2; ++qh) {
        for (int r = 0; r < 4; ++r) {
            int q = q0 + qh * 16 + quad * 4 + r;
            long orow = (pbase + q) * DD;
            for (int dt = 0; dt < 4; ++dt)
                Op[orow + dt * 16 + l15] = o[qh][dt][r];
        }
    }
    if (quad == 0) {
        for (int qh = 0; qh < 2; ++qh) {
            Mp[pbase + q0 + qh * 16 + l15] = m_q[qh];
            Lp[pbase + q0 + qh * 16 + l15] = l_q[qh];
        }
    }
}

// Kernel C: merge NSPLIT partials per query row. 16 queries/block.
__global__ __launch_bounds__(256) void combine_kernel(
    const float* __restrict__ Op, const float* __restrict__ Mp,
    const float* __restrict__ Lp, float* __restrict__ Out)
{
    int t = threadIdx.x;
    int qi = t >> 4;
    int d4 = (t & 15) * 4;
    long gq = (long)blockIdx.x * 16 + qi;    // global row in [0, BB*SS)
    int b = (int)(gq >> 12);
    int s = (int)(gq & 4095);

    float m = -1e30f;
    for (int i = 0; i < NSPLIT; ++i)
        m = fmaxf(m, Mp[((long)b * NSPLIT + i) * SS + s]);
    float l = 0.f;
    float4 o = {0.f, 0.f, 0.f, 0.f};
    for (int i = 0; i < NSPLIT; ++i) {
        long pb = ((long)b * NSPLIT + i) * SS + s;
        float a = exp2f(Mp[pb] - m);
        l = fmaf(Lp[pb], a, l);
        float4 oi = *(const float4*)(Op + pb * DD + d4);
        o.x = fmaf(oi.x, a, o.x); o.y = fmaf(oi.y, a, o.y);
        o.z = fmaf(oi.z, a, o.z); o.w = fmaf(oi.w, a, o.w);
    }
    float inv = 1.f / l;
    float4 r = {o.x * inv, o.y * inv, o.z * inv, o.w * inv};
    *(float4*)(Out + gq * DD + d4) = r;
}

extern "C" void kernel_launch(void* const* d_in, const int* in_sizes, int n_in,
                              void* d_out, int out_size, void* d_ws, size_t ws_size,
                              hipStream_t stream) {
    const float* X = (const float*)d_in[0];
    const float* R = (const float*)d_in[1];
    const float* E = (const float*)d_in[2];
    float* Out = (float*)d_out;

    const size_t N = (size_t)BB * SS * DD;
    _Float16* Qhi = (_Float16*)d_ws;
    _Float16* Qlo = Qhi + N;
    _Float16* Khi = Qlo + N;
    _Float16* Klo = Khi + N;
    _Float16* Vt  = Klo + N;                      // 10 MB fp16
    float* Op = (float*)(Vt + N);                 // BB*NSPLIT*SS*DD fp32 = 16.8 MB
    float* Mp = Op + (size_t)BB * NSPLIT * SS * DD;
    float* Lp = Mp + (size_t)BB * NSPLIT * SS;    // total ~27.3 MB

    proj_kernel<<<dim3(BB * SS / 64), 256, 0, stream>>>(X, R, E, Qhi, Qlo, Khi, Klo, Vt);
    attn_partial<<<dim3(SS / 64, NSPLIT, BB), 128, 0, stream>>>(Qhi, Qlo, Khi, Klo, Vt, Op, Mp, Lp);
    combine_kernel<<<dim3(BB * SS / 16), 256, 0, stream>>>(Op, Mp, Lp, Out);
}

// Round 8
// 123.458 us; speedup vs baseline: 1.7663x; 1.7663x over previous
//
#include <hip/hip_runtime.h>
#include <hip/hip_fp16.h>

#define BB 4
#define SS 4096
#define DD 64
#define NSPLIT 4                 // K-split factor: 1024 blocks (4/CU)
#define KT_PER (SS / 64 / NSPLIT)

typedef _Float16 half8 __attribute__((ext_vector_type(8)));
typedef _Float16 half4 __attribute__((ext_vector_type(4)));
typedef __fp16 fp16x2 __attribute__((ext_vector_type(2)));   // cvt_pkrtz return type
typedef float floatx4 __attribute__((ext_vector_type(4)));

// Kernel A: Q = X*R, K = X*E in fp32, stored as hi/lo fp16 pairs (Markidis split).
// R6 config: 16 rows/block -> 1024 blocks (4/CU).
__global__ __launch_bounds__(256) void proj_kernel(
    const float* __restrict__ X, const float* __restrict__ R, const float* __restrict__ E,
    _Float16* __restrict__ Qhi, _Float16* __restrict__ Qlo,
    _Float16* __restrict__ Khi, _Float16* __restrict__ Klo,
    _Float16* __restrict__ Vt)
{
    __shared__ float Rs[64][64];
    __shared__ float Es[64][64];
    __shared__ float Xs[16][68];     // pad 68 breaks stride-64 conflicts on transposed reads
    int t = threadIdx.x;
    long rowbase = (long)blockIdx.x * 16;

    for (int j = 0; j < 4; ++j) {
        int idx = j * 256 + t;       // 1024 float4 per 64x64 matrix
        int r = idx >> 4;
        int c = (idx & 15) * 4;
        *(float4*)&Rs[r][c] = ((const float4*)R)[idx];
        *(float4*)&Es[r][c] = ((const float4*)E)[idx];
    }
    *(float4*)&Xs[t >> 4][(t & 15) * 4] = ((const float4*)(X + rowbase * 64))[t];
    __syncthreads();

    int row = t >> 4;                // 0..15
    int c0 = (t & 15) * 4;           // 0..60
    float q[4] = {0.f, 0.f, 0.f, 0.f}, k[4] = {0.f, 0.f, 0.f, 0.f};
#pragma unroll 4
    for (int d = 0; d < 64; ++d) {
        float x = Xs[row][d];
        float4 rv = *(const float4*)&Rs[d][c0];   // ds_read_b128
        float4 ev = *(const float4*)&Es[d][c0];
        q[0] = fmaf(x, rv.x, q[0]); q[1] = fmaf(x, rv.y, q[1]);
        q[2] = fmaf(x, rv.z, q[2]); q[3] = fmaf(x, rv.w, q[3]);
        k[0] = fmaf(x, ev.x, k[0]); k[1] = fmaf(x, ev.y, k[1]);
        k[2] = fmaf(x, ev.z, k[2]); k[3] = fmaf(x, ev.w, k[3]);
    }
    long gq = (rowbase + row) * 64 + c0;
    half4 qh, ql, kh, kl;
#pragma unroll
    for (int j = 0; j < 4; ++j) {
        _Float16 h = (_Float16)q[j];
        qh[j] = h; ql[j] = (_Float16)(q[j] - (float)h);
        h = (_Float16)k[j];
        kh[j] = h; kl[j] = (_Float16)(k[j] - (float)h);
    }
    *(half4*)(Qhi + gq) = qh; *(half4*)(Qlo + gq) = ql;
    *(half4*)(Khi + gq) = kh; *(half4*)(Klo + gq) = kl;

    // V^T: Vt[b][d][s] = X[b][s][d] fp16
    int d = t >> 2;                  // 0..63
    int si = (t & 3) * 4;            // 0..12
    int b = (int)(rowbase >> 12);
    int sbase = (int)(rowbase & 4095);
    half4 v;
#pragma unroll
    for (int j = 0; j < 4; ++j) v[j] = (_Float16)Xs[si + j][d];
    *(half4*)(Vt + ((long)(b * 64 + d)) * SS + sbase + si) = v;
}

#define L2E 1.44269504088896340736f

// DMA helper: 16 B per lane, HBM -> LDS. LDS dest = wave-uniform base + lane*16.
__device__ __forceinline__ void glds16(const _Float16* g, _Float16* l) {
    __builtin_amdgcn_global_load_lds(
        (const __attribute__((address_space(1))) unsigned*)g,
        (__attribute__((address_space(3))) unsigned*)l, 16, 0, 0);
}

// Kernel B: flash attention partial over 1/NSPLIT of the keys.
// 128 threads = 2 waves x 32 queries. S^T form (A=K, B=Q): per-lane softmax.
// K/V tiles staged by global_load_lds DMA (zero staging VGPRs - the R7 scratch
// blowup is structurally impossible). Unpadded LDS + XOR-swizzled 16B blocks:
// physical block p = logical ^ (row&7); DMA lane fetches the swizzled global
// block, frag reads XOR the block index -> 2-way conflicts (free).
__global__ __launch_bounds__(128, 2) void attn_partial(
    const _Float16* __restrict__ Qhi, const _Float16* __restrict__ Qlo,
    const _Float16* __restrict__ Khi, const _Float16* __restrict__ Klo,
    const _Float16* __restrict__ Vt,
    float* __restrict__ Op, float* __restrict__ Mp, float* __restrict__ Lp)
{
    __shared__ _Float16 Ksh[64 * 64];    // [row=key][64 d], swizzled blocks
    __shared__ _Float16 Ksl[64 * 64];
    __shared__ _Float16 Vs[64 * 64];     // [row=d][64 key], swizzled blocks
    __shared__ _Float16 Ps[2][32][72];   // [wave][query][key], padded (ds_write path)

    int t = threadIdx.x;
    int wave = t >> 6;
    int lane = t & 63;
    int l15 = lane & 15;
    int quad = lane >> 4;
    int split = blockIdx.y;
    int b = blockIdx.z;
    int q0 = blockIdx.x * 64 + wave * 32;

    // Q fragments (B-operand for S^T), two 16-query halves per wave
    half8 qah0, qah1, qbh0, qbh1, qal0, qal1, qbl0, qbl1;
    {
        long qrow = ((long)b * SS + q0 + l15) * DD;
        qah0 = *(const half8*)(Qhi + qrow + quad * 8);
        qah1 = *(const half8*)(Qhi + qrow + 32 + quad * 8);
        qal0 = *(const half8*)(Qlo + qrow + quad * 8);
        qal1 = *(const half8*)(Qlo + qrow + 32 + quad * 8);
        long qrow2 = qrow + 16 * DD;
        qbh0 = *(const half8*)(Qhi + qrow2 + quad * 8);
        qbh1 = *(const half8*)(Qhi + qrow2 + 32 + quad * 8);
        qbl0 = *(const half8*)(Qlo + qrow2 + quad * 8);
        qbl1 = *(const half8*)(Qlo + qrow2 + 32 + quad * 8);
    }

    floatx4 o[2][4];
#pragma unroll
    for (int qh = 0; qh < 2; ++qh)
#pragma unroll
        for (int i = 0; i < 4; ++i) o[qh][i] = (floatx4){0.f, 0.f, 0.f, 0.f};
    float m_q[2] = {-1e30f, -1e30f};
    float l_q[2] = {0.f, 0.f};

    const float scale = 0.125f * L2E;

    // DMA lane geometry: chunk c covers rows c*8..c*8+7 (1 KB). Wave w owns
    // chunks w*4..w*4+3. Lane: row = c*8 + (lane>>3), fetches swizzled block.
    int grow = lane >> 3;                     // 0..7
    int gblk = (lane & 7) ^ grow;             // logical block to fetch
    int rm = l15 & 7;
    int p0h = ((quad ^ rm) << 3);             // physical half-offset, logical blk=quad

    int kt = split * KT_PER;
    for (int i = 0; i < KT_PER; ++i, ++kt) {
        __syncthreads();                      // prev tile's reads drained
        // issue DMA for this tile (12 instrs/wave, no data registers)
        {
            long ktile = ((long)b * SS + (long)kt * 64) * DD;   // contiguous 8 KB
            const _Float16* khs = Khi + ktile;
            const _Float16* kls = Klo + ktile;
            const _Float16* vtb = Vt + (long)b * 64 * SS + kt * 64;
#pragma unroll
            for (int j = 0; j < 4; ++j) {
                int c = wave * 4 + j;
                int row = c * 8 + grow;
                long goff = (long)row * 64 + gblk * 8;
                glds16(khs + goff, &Ksh[c * 512]);
                glds16(kls + goff, &Ksl[c * 512]);
                glds16(vtb + (long)row * SS + gblk * 8, &Vs[c * 512]);
            }
        }
        __syncthreads();                      // waitcnt vmcnt(0) + barrier: tile ready

        // S^T = K Q^T (fp32-accurate via hi/lo): C[key=quad*4+r][query=l15]
        // One K-fragment read feeds BOTH query halves.
        floatx4 s[2][4];
#pragma unroll
        for (int ct = 0; ct < 4; ++ct) {
            int rowb = (ct * 16 + l15) * 64;
            half8 ka0h = *(const half8*)&Ksh[rowb + p0h];
            half8 ka1h = *(const half8*)&Ksh[rowb + (p0h ^ 32)];
            half8 ka0l = *(const half8*)&Ksl[rowb + p0h];
            half8 ka1l = *(const half8*)&Ksl[rowb + (p0h ^ 32)];
            floatx4 acc0 = {0.f, 0.f, 0.f, 0.f};
            acc0 = __builtin_amdgcn_mfma_f32_16x16x32_f16(ka0h, qah0, acc0, 0, 0, 0);
            acc0 = __builtin_amdgcn_mfma_f32_16x16x32_f16(ka1h, qah1, acc0, 0, 0, 0);
            acc0 = __builtin_amdgcn_mfma_f32_16x16x32_f16(ka0h, qal0, acc0, 0, 0, 0);
            acc0 = __builtin_amdgcn_mfma_f32_16x16x32_f16(ka1h, qal1, acc0, 0, 0, 0);
            acc0 = __builtin_amdgcn_mfma_f32_16x16x32_f16(ka0l, qah0, acc0, 0, 0, 0);
            acc0 = __builtin_amdgcn_mfma_f32_16x16x32_f16(ka1l, qah1, acc0, 0, 0, 0);
            s[0][ct] = acc0;
            floatx4 acc1 = {0.f, 0.f, 0.f, 0.f};
            acc1 = __builtin_amdgcn_mfma_f32_16x16x32_f16(ka0h, qbh0, acc1, 0, 0, 0);
            acc1 = __builtin_amdgcn_mfma_f32_16x16x32_f16(ka1h, qbh1, acc1, 0, 0, 0);
            acc1 = __builtin_amdgcn_mfma_f32_16x16x32_f16(ka0h, qbl0, acc1, 0, 0, 0);
            acc1 = __builtin_amdgcn_mfma_f32_16x16x32_f16(ka1h, qbl1, acc1, 0, 0, 0);
            acc1 = __builtin_amdgcn_mfma_f32_16x16x32_f16(ka0l, qbh0, acc1, 0, 0, 0);
            acc1 = __builtin_amdgcn_mfma_f32_16x16x32_f16(ka1l, qbh1, acc1, 0, 0, 0);
            s[1][ct] = acc1;
        }

        // per-lane softmax for each query half (query = q0 + qh*16 + l15)
#pragma unroll
        for (int qh = 0; qh < 2; ++qh) {
            float mt = s[qh][0][0];
#pragma unroll
            for (int ct = 0; ct < 4; ++ct)
#pragma unroll
                for (int r = 0; r < 4; ++r)
                    mt = fmaxf(mt, s[qh][ct][r]);
            mt = fmaxf(mt, __shfl_xor(mt, 16));
            mt = fmaxf(mt, __shfl_xor(mt, 32));
            mt *= scale;
            float mn = fmaxf(m_q[qh], mt);
            float alpha = exp2f(m_q[qh] - mn);   // 0 on first tile
            m_q[qh] = mn;

            float rs = 0.f;
#pragma unroll
            for (int ct = 0; ct < 4; ++ct) {
                float p0 = exp2f(s[qh][ct][0] * scale - mn);
                float p1 = exp2f(s[qh][ct][1] * scale - mn);
                float p2 = exp2f(s[qh][ct][2] * scale - mn);
                float p3 = exp2f(s[qh][ct][3] * scale - mn);
                rs += (p0 + p1) + (p2 + p3);
                union { fp16x2 h2[2]; half4 h4; } u;
                u.h2[0] = __builtin_amdgcn_cvt_pkrtz(p0, p1);
                u.h2[1] = __builtin_amdgcn_cvt_pkrtz(p2, p3);
                *(half4*)&Ps[wave][qh * 16 + l15][ct * 16 + quad * 4] = u.h4;
            }
            rs += __shfl_xor(rs, 16);            // cross-quad SUM (full 64-key row)
            rs += __shfl_xor(rs, 32);
            l_q[qh] = l_q[qh] * alpha + rs;

            // rescale O (C-layout rows = query quad*4+r)
#pragma unroll
            for (int r = 0; r < 4; ++r) {
                float a = __shfl(alpha, quad * 4 + r);
                o[qh][0][r] *= a; o[qh][1][r] *= a;
                o[qh][2][r] *= a; o[qh][3][r] *= a;
            }
        }

        // O += P V : A = Ps (m=query, k=key), B = Vs rows (n=d, k=key, swizzled)
#pragma unroll
        for (int h = 0; h < 2; ++h) {
            half8 pa0 = *(const half8*)&Ps[wave][l15][h * 32 + quad * 8];
            half8 pa1 = *(const half8*)&Ps[wave][16 + l15][h * 32 + quad * 8];
#pragma unroll
            for (int dt = 0; dt < 4; ++dt) {
                int rowb = (dt * 16 + l15) * 64;
                half8 vb = *(const half8*)&Vs[rowb + (p0h ^ (h << 5))];
                o[0][dt] = __builtin_amdgcn_mfma_f32_16x16x32_f16(pa0, vb, o[0][dt], 0, 0, 0);
                o[1][dt] = __builtin_amdgcn_mfma_f32_16x16x32_f16(pa1, vb, o[1][dt], 0, 0, 0);
            }
        }
    }

    // store unnormalized partial O (rows = query qh*16+quad*4+r) and (m, l)
    long pbase = ((long)b * NSPLIT + split) * SS;
#pragma unroll
    for (int qh = 0; qh < 2; ++qh) {
#pragma unroll
        for (int r = 0; r < 4; ++r) {
            int q = q0 + qh * 16 + quad * 4 + r;
            long orow = (pbase + q) * DD;
#pragma unroll
            for (int dt = 0; dt < 4; ++dt)
                Op[orow + dt * 16 + l15] = o[qh][dt][r];
        }
    }
    if (quad == 0) {
        Mp[pbase + q0 + l15] = m_q[0];
        Lp[pbase + q0 + l15] = l_q[0];
        Mp[pbase + q0 + 16 + l15] = m_q[1];
        Lp[pbase + q0 + 16 + l15] = l_q[1];
    }
}

// Kernel C: merge NSPLIT partials per query row. 16 queries/block.
__global__ __launch_bounds__(256) void combine_kernel(
    const float* __restrict__ Op, const float* __restrict__ Mp,
    const float* __restrict__ Lp, float* __restrict__ Out)
{
    int t = threadIdx.x;
    int qi = t >> 4;
    int d4 = (t & 15) * 4;
    long gq = (long)blockIdx.x * 16 + qi;    // global row in [0, BB*SS)
    int b = (int)(gq >> 12);
    int s = (int)(gq & 4095);

    float m = -1e30f;
    for (int i = 0; i < NSPLIT; ++i)
        m = fmaxf(m, Mp[((long)b * NSPLIT + i) * SS + s]);
    float l = 0.f;
    float4 o = {0.f, 0.f, 0.f, 0.f};
    for (int i = 0; i < NSPLIT; ++i) {
        long pb = ((long)b * NSPLIT + i) * SS + s;
        float a = exp2f(Mp[pb] - m);
        l = fmaf(Lp[pb], a, l);
        float4 oi = *(const float4*)(Op + pb * DD + d4);
        o.x = fmaf(oi.x, a, o.x); o.y = fmaf(oi.y, a, o.y);
        o.z = fmaf(oi.z, a, o.z); o.w = fmaf(oi.w, a, o.w);
    }
    float inv = 1.f / l;
    float4 r = {o.x * inv, o.y * inv, o.z * inv, o.w * inv};
    *(float4*)(Out + gq * DD + d4) = r;
}

extern "C" void kernel_launch(void* const* d_in, const int* in_sizes, int n_in,
                              void* d_out, int out_size, void* d_ws, size_t ws_size,
                              hipStream_t stream) {
    const float* X = (const float*)d_in[0];
    const float* R = (const float*)d_in[1];
    const float* E = (const float*)d_in[2];
    float* Out = (float*)d_out;

    const size_t N = (size_t)BB * SS * DD;
    _Float16* Qhi = (_Float16*)d_ws;
    _Float16* Qlo = Qhi + N;
    _Float16* Khi = Qlo + N;
    _Float16* Klo = Khi + N;
    _Float16* Vt  = Klo + N;                      // 10 MB fp16
    float* Op = (float*)(Vt + N);                 // BB*NSPLIT*SS*DD fp32 = 16.8 MB
    float* Mp = Op + (size_t)BB * NSPLIT * SS * DD;
    float* Lp = Mp + (size_t)BB * NSPLIT * SS;    // total ~27.3 MB

    proj_kernel<<<dim3(BB * SS / 16), 256, 0, stream>>>(X, R, E, Qhi, Qlo, Khi, Klo, Vt);
    attn_partial<<<dim3(SS / 64, NSPLIT, BB), 128, 0, stream>>>(Qhi, Qlo, Khi, Klo, Vt, Op, Mp, Lp);
    combine_kernel<<<dim3(BB * SS / 16), 256, 0, stream>>>(Op, Mp, Lp, Out);
}